// Round 7
// baseline (11579.279 us; speedup 1.0000x reference)
//
#include <hip/hip_runtime.h>
#include <hip/hip_bf16.h>

#define B_  256
#define T_  1024
#define D_  256
#define H_  512
#define G_  2048   // 4*H
#define KT_ 768    // H + D

// ws layout (bytes)
#define WPACK_OFF 0                        // 2048*768*2 = 3145728
#define BIAS_OFF  3145728                  // 2048*4     = 8192
#define H0_OFF    (BIAS_OFF + 8192)        // 256*512*2  = 262144
#define H1_OFF    (H0_OFF + 262144)
#define C_OFF     (H1_OFF + 262144)        // 256*512*4  = 524288 (fallback path only)
#define FLAG_OFF  (C_OFF + 524288)         // flags: 64 x 16 uints

typedef __attribute__((ext_vector_type(8))) short bf16x8;
typedef __attribute__((ext_vector_type(4))) float f32x4;
typedef __attribute__((ext_vector_type(4))) unsigned int u32x4;   // asm-safe 16B vector

__device__ __forceinline__ unsigned short f2bf(float f) {
    unsigned int u = __float_as_uint(f);
    u = (u + 0x7fffu + ((u >> 16) & 1u)) >> 16;   // RNE
    return (unsigned short)u;
}
__device__ __forceinline__ float bf2f(unsigned short s) {
    return __uint_as_float(((unsigned int)s) << 16);
}
__device__ __forceinline__ float sigm(float v) { return 1.0f / (1.0f + __expf(-v)); }
__device__ __forceinline__ float tanh_(float v) { return 2.0f / (1.0f + __expf(-2.0f * v)) - 1.0f; }

// ---- prep: pack [W_hh | W_ih] rows into bf16 Wpack[2048][768] ----
__global__ __launch_bounds__(256) void build_wpack(const float* __restrict__ Whh,
                                                   const float* __restrict__ Wih,
                                                   unsigned short* __restrict__ wpack) {
    int idx = blockIdx.x * 256 + threadIdx.x;      // 0..196607, each = 8 elems
    int g = idx / 96, cc = idx % 96, k = cc * 8;
    const float* src = (k < H_) ? (Whh + (size_t)g * H_ + k)
                                : (Wih + (size_t)g * D_ + (k - H_));
    union { unsigned short us[8]; uint4 v; } u;
#pragma unroll
    for (int i = 0; i < 8; ++i) u.us[i] = f2bf(src[i]);
    *(uint4*)(wpack + (size_t)idx * 8) = u.v;
}

// ---- prep: zero h0/h1/c, build bias, zero flags ----
__global__ __launch_bounds__(256) void init_misc(const float* __restrict__ bih,
                                                 const float* __restrict__ bhh,
                                                 float* __restrict__ bias,
                                                 unsigned int* __restrict__ zreg,
                                                 unsigned int* __restrict__ flags) {
    int gid = blockIdx.x * 256 + threadIdx.x;      // grid 1024 -> 262144
    zreg[gid] = 0u;                                // h0+h1+c region (1 MB)
    if (gid < G_) bias[gid] = bih[gid] + bhh[gid];
    if (gid < 4096) flags[gid] = 0u;
}

// ============ persistent cooperative LSTM ============
// grid 64: rg = bid&3 (rowgroup, 64 batch rows), cg = bid>>2 (32 j-cols).
// 512 threads = 8 waves; wave w: g = w>>1 (gate), jt = w&1 (16-col j-tile).
// Per wave: 4 row-tiles x 1 col-tile x 24 K-slices = 96 MFMA/step (~1800 cy)
// -- sized to hide the LLC exchange latency. W fragments = 96 VGPR, loaded
// once. c lives in 4 regs/thread. h exchange: 16B sc0/sc1 asm loads
// (early-clobber outputs), 8B relaxed-atomic stores; sync via per-block
// padded flags, relaxed stores ordered by __syncthreads vmcnt drain
// (NO release -> no per-step L2 writeback).
__global__ __launch_bounds__(512, 2) void lstm_persist(
    const float* __restrict__ x,
    const unsigned short* __restrict__ wpack,
    const float* __restrict__ bias,
    unsigned short* __restrict__ h0,
    unsigned short* __restrict__ h1,
    unsigned int* __restrict__ flags)
{
    __shared__ __align__(16) unsigned char As[64 * 1536];   // [64 rows][768 k] bf16, XOR-swizzled
    __shared__ float Pc[4][64][33];                          // per-gate gate sums (pad 33)
    __shared__ __align__(16) unsigned short Hs[64][32];      // new h tile (bf16)

    const int tid  = threadIdx.x;
    const int lane = tid & 63, w = tid >> 6;
    const int g = w >> 1, jt = w & 1;
    const int rg = blockIdx.x & 3, cg = blockIdx.x >> 2;
    const int r0 = rg * 64;

    // ---- load this wave's W fragments into registers (once): 96 VGPR ----
    bf16x8 bfr[24];
    {
        const unsigned short* wrow = wpack
            + (size_t)(g * H_ + cg * 32 + jt * 16 + (lane & 15)) * KT_ + ((lane >> 4) * 8);
#pragma unroll
        for (int ks = 0; ks < 24; ++ks) bfr[ks] = *(const bf16x8*)(wrow + ks * 32);
    }

    // ---- per-thread epilogue constants (j fixed, 4 rows per thread) ----
    const int ej = tid & 31;          // j within 32-col tile
    const float bI = bias[0 * H_ + cg * 32 + ej];
    const float bF = bias[1 * H_ + cg * 32 + ej];
    const float bG = bias[2 * H_ + cg * 32 + ej];
    const float bO = bias[3 * H_ + cg * 32 + ej];
    float c_reg[4] = {0.f, 0.f, 0.f, 0.f};

    const int koff = (lane >> 4) * 16;       // byte offset within 64B k-step
    const int asw  = ((lane & 7) << 4);      // row&7 == (lane&15)&7 for all row-tiles

    // ---- x prefetch (cached): 32 floats/thread (row tid>>3, cols (tid&7)*32) ----
    const int xrow = tid >> 3;               // 0..63
    const int xd0  = (tid & 7) * 32;         // float index within row
    const float* xbase = x + (size_t)(r0 + xrow) * T_ * D_ + xd0;
    float4 pa[8];
#pragma unroll
    for (int q = 0; q < 8; ++q) pa[q] = *(const float4*)(xbase + q * 4);

    unsigned int* myflag   = flags + (size_t)(rg * 16 + cg) * 16;
    unsigned int* pollflag = flags + (size_t)(rg * 16 + (lane & 15)) * 16;

    for (int t = 0; t < T_; ++t) {
        const unsigned short* hin = (t & 1) ? h1 : h0;
        unsigned short*      hout = (t & 1) ? h0 : h1;

        // A: stage x(t) from prefetched regs -> As.x (k 512..767); prefetch x(t+1)
        {
            int xb = xrow * 1536 + 1024 + xd0 * 2;
            int xsw = (xrow & 7) << 4;
#pragma unroll
            for (int q = 0; q < 4; ++q) {
                union { unsigned short us[8]; uint4 v; } u;
                float4 a = pa[q * 2], b = pa[q * 2 + 1];
                u.us[0] = f2bf(a.x); u.us[1] = f2bf(a.y); u.us[2] = f2bf(a.z); u.us[3] = f2bf(a.w);
                u.us[4] = f2bf(b.x); u.us[5] = f2bf(b.y); u.us[6] = f2bf(b.z); u.us[7] = f2bf(b.w);
                *(uint4*)(As + ((xb + q * 16) ^ xsw)) = u.v;
            }
        }
        if (t + 1 < T_) {
            const float* sp = xbase + (size_t)(t + 1) * D_;
#pragma unroll
            for (int q = 0; q < 8; ++q) pa[q] = *(const float4*)(sp + q * 4);
        }
        __syncthreads();

        // B: x-part MFMAs (ks 16..23, 4 row-tiles) -- no h dependency
        f32x4 acc[4];
#pragma unroll
        for (int rt = 0; rt < 4; ++rt) acc[rt] = (f32x4){0.f, 0.f, 0.f, 0.f};
#pragma unroll
        for (int ks = 16; ks < 24; ++ks) {
#pragma unroll
            for (int rt = 0; rt < 4; ++rt) {
                int arow = rt * 16 + (lane & 15);
                bf16x8 av = *(const bf16x8*)(As + ((arow * 1536 + ks * 64 + koff) ^ asw));
                acc[rt] = __builtin_amdgcn_mfma_f32_16x16x32_bf16(av, bfr[ks], acc[rt], 0, 0, 0);
            }
        }

        // C: ALL waves poll the 16 rowgroup flags (lanes parallel, no RMW)
        if (t > 0) {
            while (true) {
                unsigned int f = __hip_atomic_load(pollflag, __ATOMIC_RELAXED,
                                                   __HIP_MEMORY_SCOPE_AGENT);
                if (__all((int)(f >= (unsigned)t))) break;
                __builtin_amdgcn_s_sleep(1);
            }
        }

        // D: coherent 16B h loads (8/thread, 64KB total) -> As.h
        {
            u32x4 hv[8];
            const unsigned short* hb = hin + (size_t)r0 * H_;
#pragma unroll
            for (int p = 0; p < 8; ++p) {
                int c = p * 512 + tid;            // 0..4095 chunks of 16B
                int row = c >> 6, off = c & 63;
                const u32x4* ptr = (const u32x4*)(hb + (size_t)row * H_ + off * 8);
                asm volatile("global_load_dwordx4 %0, %1, off sc0 sc1"
                             : "=&v"(hv[p]) : "v"(ptr));
            }
            asm volatile("s_waitcnt vmcnt(0)" ::: "memory");
            __builtin_amdgcn_sched_barrier(0);
#pragma unroll
            for (int p = 0; p < 8; ++p) {
                int c = p * 512 + tid;
                int row = c >> 6, off = c & 63;
                *(u32x4*)(As + ((row * 1536 + off * 16) ^ ((row & 7) << 4))) = hv[p];
            }
        }
        __syncthreads();

        // E: h-part MFMAs (ks 0..15, 4 row-tiles)
#pragma unroll
        for (int ks = 0; ks < 16; ++ks) {
#pragma unroll
            for (int rt = 0; rt < 4; ++rt) {
                int arow = rt * 16 + (lane & 15);
                bf16x8 av = *(const bf16x8*)(As + ((arow * 1536 + ks * 64 + koff) ^ asw));
                acc[rt] = __builtin_amdgcn_mfma_f32_16x16x32_bf16(av, bfr[ks], acc[rt], 0, 0, 0);
            }
        }
        // F: dump gate sums (C layout: col=lane&15, row=(lane>>4)*4+reg)
#pragma unroll
        for (int rt = 0; rt < 4; ++rt) {
#pragma unroll
            for (int reg = 0; reg < 4; ++reg) {
                int crow = rt * 16 + ((lane >> 4) * 4) + reg;
                Pc[g][crow][jt * 16 + (lane & 15)] = acc[rt][reg];
            }
        }
        __syncthreads();

        // G: cell update; thread owns (4 rows, ej); c stays in registers
#pragma unroll
        for (int p = 0; p < 4; ++p) {
            int row = p * 16 + (tid >> 5);
            float gi = Pc[0][row][ej] + bI;
            float gf = Pc[1][row][ej] + bF;
            float gg = Pc[2][row][ej] + bG;
            float go = Pc[3][row][ej] + bO;
            float I = sigm(gi), F = sigm(gf), Gv = tanh_(gg), O = sigm(go);
            c_reg[p] = F * c_reg[p] + I * Gv;
            Hs[row][ej] = f2bf(O * tanh_(c_reg[p]));
        }
        __syncthreads();

        // H: store the 4KB h tile (1x8B per thread, coherent relaxed), drain
        //    via __syncthreads (per-wave vmcnt(0)), then tid 0 publishes flag.
        {
            int row = tid >> 3, part = tid & 7;
            unsigned long long v = *(const unsigned long long*)(&Hs[row][part * 4]);
            __hip_atomic_store(
                (unsigned long long*)(hout + (size_t)(r0 + row) * H_ + cg * 32) + part,
                v, __ATOMIC_RELAXED, __HIP_MEMORY_SCOPE_AGENT);
        }
        __syncthreads();   // all h stores drained before flag
        if (tid == 0)
            __hip_atomic_store(myflag, (unsigned)(t + 1), __ATOMIC_RELAXED,
                               __HIP_MEMORY_SCOPE_AGENT);
    }
}

// ============ fallback per-step kernel (round-1, known passing) ============
__global__ __launch_bounds__(256) void lstm_step(const float* __restrict__ x,
                                                 const unsigned short* __restrict__ wpack,
                                                 const float* __restrict__ bias,
                                                 const unsigned short* __restrict__ hin,
                                                 unsigned short* __restrict__ hout,
                                                 float* __restrict__ cbuf,
                                                 int t) {
    __shared__ __align__(16) unsigned char As[64 * 1536];
    __shared__ __align__(16) unsigned char Ws[128 * 256];

    const int tid = threadIdx.x;
    const int w = tid >> 6, lane = tid & 63;
    const int r0 = blockIdx.x * 64;
    const int j0 = blockIdx.y * 32;

#pragma unroll
    for (int p = 0; p < 16; ++p) {
        int idx = p * 256 + tid;
        int row = idx >> 6, seg = idx & 63;
        uint4 v = *(const uint4*)(hin + (size_t)(r0 + row) * H_ + seg * 8);
        *(uint4*)(As + (((row * 1536) + seg * 16) ^ ((row & 7) << 4))) = v;
    }
#pragma unroll
    for (int p = 0; p < 8; ++p) {
        int idx = p * 256 + tid;
        int row = idx >> 5, seg = idx & 31;
        const float* sp = x + ((size_t)(r0 + row) * T_ + t) * D_ + seg * 8;
        float4 a = *(const float4*)sp;
        float4 b = *(const float4*)(sp + 4);
        union { unsigned short us[8]; uint4 v; } u;
        u.us[0] = f2bf(a.x); u.us[1] = f2bf(a.y); u.us[2] = f2bf(a.z); u.us[3] = f2bf(a.w);
        u.us[4] = f2bf(b.x); u.us[5] = f2bf(b.y); u.us[6] = f2bf(b.z); u.us[7] = f2bf(b.w);
        *(uint4*)(As + (((row * 1536) + 1024 + seg * 16) ^ ((row & 7) << 4))) = u.v;
    }
    __syncthreads();

    f32x4 acc[8];
#pragma unroll
    for (int i = 0; i < 8; ++i) acc[i] = (f32x4){0.f, 0.f, 0.f, 0.f};

    for (int kc = 0; kc < 6; ++kc) {
#pragma unroll
        for (int p = 0; p < 8; ++p) {
            int idx = p * 256 + tid;
            int n = idx >> 4, seg = idx & 15;
            int g = n >> 5, jj = n & 31;
            uint4 v = *(const uint4*)(wpack + (size_t)(g * H_ + j0 + jj) * KT_ + kc * 128 + seg * 8);
            *(uint4*)(Ws + (((n * 256) + seg * 16) ^ ((n & 7) << 4))) = v;
        }
        __syncthreads();
#pragma unroll
        for (int ks = 0; ks < 4; ++ks) {
            int row = w * 16 + (lane & 15);
            int kb = (kc * 128 + ks * 32 + ((lane >> 4) * 8)) * 2;
            bf16x8 av = *(const bf16x8*)(As + ((row * 1536 + kb) ^ ((row & 7) << 4)));
            int kwb = (ks * 32 + ((lane >> 4) * 8)) * 2;
#pragma unroll
            for (int nt = 0; nt < 8; ++nt) {
                int n = (nt >> 1) * 32 + (nt & 1) * 16 + (lane & 15);
                bf16x8 bv = *(const bf16x8*)(Ws + ((n * 256 + kwb) ^ ((n & 7) << 4)));
                acc[nt] = __builtin_amdgcn_mfma_f32_16x16x32_bf16(av, bv, acc[nt], 0, 0, 0);
            }
        }
        __syncthreads();
    }

#pragma unroll
    for (int jt = 0; jt < 2; ++jt) {
        int jc = j0 + jt * 16 + (lane & 15);
        float bi = bias[jc], bf = bias[H_ + jc], bg = bias[2 * H_ + jc], bo = bias[3 * H_ + jc];
        f32x4 ai = acc[0 * 2 + jt];
        f32x4 af = acc[1 * 2 + jt];
        f32x4 ag = acc[2 * 2 + jt];
        f32x4 ao = acc[3 * 2 + jt];
#pragma unroll
        for (int reg = 0; reg < 4; ++reg) {
            int rb = r0 + w * 16 + ((lane >> 4) * 4) + reg;
            float I = sigm(ai[reg] + bi);
            float F = sigm(af[reg] + bf);
            float Gv = tanh_(ag[reg] + bg);
            float O = sigm(ao[reg] + bo);
            size_t ci = (size_t)rb * H_ + jc;
            float cn = F * cbuf[ci] + I * Gv;
            cbuf[ci] = cn;
            hout[ci] = f2bf(O * tanh_(cn));
        }
    }
}

// ---- final: out = sigmoid(h @ W_out^T + b_out), [256,2] ----
__global__ __launch_bounds__(256) void classify(const unsigned short* __restrict__ hbuf,
                                                const float* __restrict__ Wout,
                                                const float* __restrict__ bout,
                                                float* __restrict__ out) {
    int r = threadIdx.x;
    float a0 = 0.f, a1 = 0.f;
    for (int kk = 0; kk < H_ / 8; ++kk) {
        union { unsigned short us[8]; uint4 v; } u;
        u.v = *(const uint4*)(hbuf + (size_t)r * H_ + kk * 8);
#pragma unroll
        for (int i = 0; i < 8; ++i) {
            float hf = bf2f(u.us[i]);
            int k = kk * 8 + i;
            a0 += hf * Wout[k];
            a1 += hf * Wout[H_ + k];
        }
    }
    out[r * 2 + 0] = sigm(a0 + bout[0]);
    out[r * 2 + 1] = sigm(a1 + bout[1]);
}

extern "C" void kernel_launch(void* const* d_in, const int* in_sizes, int n_in,
                              void* d_out, int out_size, void* d_ws, size_t ws_size,
                              hipStream_t stream) {
    const float* x    = (const float*)d_in[0];
    const float* Wih  = (const float*)d_in[1];
    const float* Whh  = (const float*)d_in[2];
    const float* bih  = (const float*)d_in[3];
    const float* bhh  = (const float*)d_in[4];
    const float* Wout = (const float*)d_in[5];
    const float* bout = (const float*)d_in[6];
    float* out = (float*)d_out;
    char* ws = (char*)d_ws;

    unsigned short* wpack = (unsigned short*)(ws + WPACK_OFF);
    float*          bias  = (float*)(ws + BIAS_OFF);
    unsigned short* h0    = (unsigned short*)(ws + H0_OFF);
    unsigned short* h1    = (unsigned short*)(ws + H1_OFF);
    float*          cbuf  = (float*)(ws + C_OFF);
    unsigned int*   flags = (unsigned int*)(ws + FLAG_OFF);

    build_wpack<<<768, 256, 0, stream>>>(Whh, Wih, wpack);
    init_misc<<<1024, 256, 0, stream>>>(bih, bhh, bias, (unsigned int*)(ws + H0_OFF), flags);

    // persistent cooperative kernel; fall back to per-step launches if rejected
    const float* xa = x; const unsigned short* wa = wpack; const float* ba = bias;
    unsigned short* h0a = h0; unsigned short* h1a = h1; unsigned int* fa = flags;
    void* args[] = { (void*)&xa, (void*)&wa, (void*)&ba, (void*)&h0a, (void*)&h1a, (void*)&fa };
    hipError_t e = hipLaunchCooperativeKernel((const void*)lstm_persist,
                                              dim3(64), dim3(512), args, 0, stream);
    if (e != hipSuccess) {
        for (int t = 0; t < T_; ++t) {
            const unsigned short* hin = (t & 1) ? h1 : h0;
            unsigned short*      hout = (t & 1) ? h0 : h1;
            lstm_step<<<dim3(4, 16), 256, 0, stream>>>(x, wpack, bias, hin, hout, cbuf, t);
        }
    }
    classify<<<1, 256, 0, stream>>>(h0, Wout, bout, out);
}

// Round 9
// 4790.483 us; speedup vs baseline: 2.4171x; 2.4171x over previous
//
#include <hip/hip_runtime.h>
#include <hip/hip_bf16.h>

#define B_  256
#define T_  1024
#define D_  256
#define H_  512
#define G_  2048   // 4*H
#define KT_ 768    // H + D

// ws layout (bytes)
#define WPACK_OFF 0                        // 2048*768*2 = 3145728
#define BIAS_OFF  3145728                  // 2048*4     = 8192
#define H0_OFF    (BIAS_OFF + 8192)        // 256*512*2  = 262144
#define H1_OFF    (H0_OFF + 262144)
#define C_OFF     (H1_OFF + 262144)        // 256*512*4  = 524288 (fallback path only)
#define FLAG_OFF  (C_OFF + 524288)         // 256 flags x 32 uints (128B apart) = 32768

typedef __attribute__((ext_vector_type(8))) short bf16x8;
typedef __attribute__((ext_vector_type(4))) float f32x4;

__device__ __forceinline__ unsigned short f2bf(float f) {
    unsigned int u = __float_as_uint(f);
    u = (u + 0x7fffu + ((u >> 16) & 1u)) >> 16;   // RNE
    return (unsigned short)u;
}
__device__ __forceinline__ float bf2f(unsigned short s) {
    return __uint_as_float(((unsigned int)s) << 16);
}
__device__ __forceinline__ float sigm(float v) { return 1.0f / (1.0f + __expf(-v)); }
__device__ __forceinline__ float tanh_(float v) { return 2.0f / (1.0f + __expf(-2.0f * v)) - 1.0f; }

// ---- prep: pack [W_hh | W_ih] rows into bf16 Wpack[2048][768] ----
__global__ __launch_bounds__(256) void build_wpack(const float* __restrict__ Whh,
                                                   const float* __restrict__ Wih,
                                                   unsigned short* __restrict__ wpack) {
    int idx = blockIdx.x * 256 + threadIdx.x;      // 0..196607, each = 8 elems
    int g = idx / 96, cc = idx % 96, k = cc * 8;
    const float* src = (k < H_) ? (Whh + (size_t)g * H_ + k)
                                : (Wih + (size_t)g * D_ + (k - H_));
    union { unsigned short us[8]; uint4 v; } u;
#pragma unroll
    for (int i = 0; i < 8; ++i) u.us[i] = f2bf(src[i]);
    *(uint4*)(wpack + (size_t)idx * 8) = u.v;
}

// ---- prep: zero h0/h1/c, build bias, zero flags ----
__global__ __launch_bounds__(256) void init_misc(const float* __restrict__ bih,
                                                 const float* __restrict__ bhh,
                                                 float* __restrict__ bias,
                                                 unsigned int* __restrict__ zreg,
                                                 unsigned int* __restrict__ flags) {
    int gid = blockIdx.x * 256 + threadIdx.x;      // grid 1024 -> 262144
    zreg[gid] = 0u;                                // h0+h1+c region (1 MB)
    if (gid < G_) bias[gid] = bih[gid] + bhh[gid];
    if (gid < 8192) flags[gid] = 0u;
}

// ============ persistent cooperative LSTM ============
// grid 256: rg = bid&7 (rowgroup, 32 batch rows), cg = bid>>3 (16 j-cols).
// 512 threads = 8 waves; wave w: np = w>>1 (gate), rt = w&1 (16-row tile).
// W fragments (24 x bf16x8 = 96 VGPR) in registers for the whole T loop.
// c lives in 1 reg/thread.
// h protocol (message passing, placement-independent):
//   producer: relaxed agent-scope 8B stores (write-through to LLC)
//             -> __syncthreads (vmcnt drain, all waves) -> relaxed flag store.
//   consumer: relaxed flag poll -> ONE acquire load (emits L1+L2 inv)
//             -> plain cached uint4 h loads (L2 serves co-located blocks).
// LDS padded >80KB so only 1 block/CU fits -> 256 blocks spread over 256 CUs.
__global__ __launch_bounds__(512, 2) void lstm_persist(
    const float* __restrict__ x,
    const unsigned short* __restrict__ wpack,
    const float* __restrict__ bias,
    unsigned short* __restrict__ h0,
    unsigned short* __restrict__ h1,
    unsigned int* __restrict__ flags)
{
    __shared__ __align__(16) unsigned char As[32 * 1536];   // [32 rows][768 k] bf16, XOR-swizzled
    __shared__ float Pc[4][32][18];                          // per-gate partial sums
    __shared__ __align__(16) unsigned short Hs[32][16];      // new h tile (bf16)
    __shared__ unsigned char lds_pad[28 * 1024];             // force 1 block/CU (>80KB total)

    const int tid  = threadIdx.x;
    const int lane = tid & 63, w = tid >> 6;
    const int np = w >> 1, rt = w & 1;
    const int rg = blockIdx.x & 7, cg = blockIdx.x >> 3;
    const int r0 = rg * 32;

    // keep lds_pad alive (branch never taken; compiler can't prove it)
    if (__float_as_uint(bias[0]) == 0xDEADBEEFu) lds_pad[tid] = (unsigned char)tid;

    // ---- load this wave's W fragments into registers (once) ----
    bf16x8 bfr[24];
    {
        const unsigned short* wrow = wpack
            + (size_t)(np * H_ + cg * 16 + (lane & 15)) * KT_ + ((lane >> 4) * 8);
#pragma unroll
        for (int ks = 0; ks < 24; ++ks) bfr[ks] = *(const bf16x8*)(wrow + ks * 32);
    }

    // ---- per-thread epilogue constants ----
    const int erow = tid >> 4;        // 0..31
    const int ejj  = tid & 15;        // 0..15
    const float bI = bias[0 * H_ + cg * 16 + ejj];
    const float bF = bias[1 * H_ + cg * 16 + ejj];
    const float bG = bias[2 * H_ + cg * 16 + ejj];
    const float bO = bias[3 * H_ + cg * 16 + ejj];
    float c_reg = 0.f;

    const int arow = rt * 16 + (lane & 15);
    const int koff = (lane >> 4) * 16;     // byte offset within 64B k-step
    const int asw  = (arow & 7) << 4;

    // ---- x prefetch (cached): 16 floats/thread ----
    const int xrow = tid >> 4;             // 0..31
    const int xd0  = (tid & 15) * 16;      // float index within row
    const float* xbase = x + (size_t)(r0 + xrow) * T_ * D_ + xd0;
    float4 pa = *(const float4*)(xbase + 0);
    float4 pb = *(const float4*)(xbase + 4);
    float4 pc2 = *(const float4*)(xbase + 8);
    float4 pd = *(const float4*)(xbase + 12);

    unsigned int* myflag   = flags + (size_t)(rg * 32 + cg) * 32;
    unsigned int* pollflag = flags + (size_t)(rg * 32 + (lane & 31)) * 32;

    for (int t = 0; t < T_; ++t) {
        const unsigned short* hin = (t & 1) ? h1 : h0;
        unsigned short*      hout = (t & 1) ? h0 : h1;

        // A: stage x(t) from prefetched regs -> As.x (k 512..767); prefetch x(t+1)
        {
            union { unsigned short us[8]; uint4 v; } u0, u1;
            u0.us[0] = f2bf(pa.x);  u0.us[1] = f2bf(pa.y);  u0.us[2] = f2bf(pa.z);  u0.us[3] = f2bf(pa.w);
            u0.us[4] = f2bf(pb.x);  u0.us[5] = f2bf(pb.y);  u0.us[6] = f2bf(pb.z);  u0.us[7] = f2bf(pb.w);
            u1.us[0] = f2bf(pc2.x); u1.us[1] = f2bf(pc2.y); u1.us[2] = f2bf(pc2.z); u1.us[3] = f2bf(pc2.w);
            u1.us[4] = f2bf(pd.x);  u1.us[5] = f2bf(pd.y);  u1.us[6] = f2bf(pd.z);  u1.us[7] = f2bf(pd.w);
            int kb = 1024 + xd0 * 2;
            int xsw = (xrow & 7) << 4;
            *(uint4*)(As + ((xrow * 1536 + kb) ^ xsw))      = u0.v;
            *(uint4*)(As + ((xrow * 1536 + kb + 16) ^ xsw)) = u1.v;
        }
        if (t + 1 < T_) {
            const float* sp = xbase + (size_t)(t + 1) * D_;
            pa = *(const float4*)(sp + 0);
            pb = *(const float4*)(sp + 4);
            pc2 = *(const float4*)(sp + 8);
            pd = *(const float4*)(sp + 12);
        }
        __syncthreads();

        // B: x-part MFMAs (ks 16..23) -- no h dependency; hides poll wait
        f32x4 acc0 = {0.f, 0.f, 0.f, 0.f}, acc1 = {0.f, 0.f, 0.f, 0.f};
#pragma unroll
        for (int ks = 16; ks < 24; ks += 2) {
            bf16x8 av0 = *(const bf16x8*)(As + ((arow * 1536 + ks * 64 + koff) ^ asw));
            bf16x8 av1 = *(const bf16x8*)(As + ((arow * 1536 + (ks + 1) * 64 + koff) ^ asw));
            acc0 = __builtin_amdgcn_mfma_f32_16x16x32_bf16(av0, bfr[ks], acc0, 0, 0, 0);
            acc1 = __builtin_amdgcn_mfma_f32_16x16x32_bf16(av1, bfr[ks + 1], acc1, 0, 0, 0);
        }

        // C: wave 0 polls the 32 rowgroup flags (relaxed), then ONE acquire
        //    load -> L1+L2 invalidate so phase D can use cached loads.
        if (w == 0 && t > 0) {
            while (true) {
                unsigned int f = __hip_atomic_load(pollflag, __ATOMIC_RELAXED,
                                                   __HIP_MEMORY_SCOPE_AGENT);
                if (__all((int)(f >= (unsigned)t))) break;
                __builtin_amdgcn_s_sleep(1);
            }
            (void)__hip_atomic_load(myflag, __ATOMIC_ACQUIRE, __HIP_MEMORY_SCOPE_AGENT);
        }
        __syncthreads();

        // D: plain cached 16B h loads (4/thread, 32KB) -> As.h
        //    (fresh after the acquire-inv; L2 serves co-located blocks)
#pragma unroll
        for (int p = 0; p < 4; ++p) {
            int c = p * 512 + tid;            // 0..2047 chunks of 16B
            int row = c >> 6, off = c & 63;
            uint4 v = *(const uint4*)(hin + (size_t)(r0 + row) * H_ + off * 8);
            *(uint4*)(As + ((row * 1536 + off * 16) ^ ((row & 7) << 4))) = v;
        }
        __syncthreads();

        // E: h-part MFMAs (ks 0..15)
#pragma unroll
        for (int ks = 0; ks < 16; ks += 2) {
            bf16x8 av0 = *(const bf16x8*)(As + ((arow * 1536 + ks * 64 + koff) ^ asw));
            bf16x8 av1 = *(const bf16x8*)(As + ((arow * 1536 + (ks + 1) * 64 + koff) ^ asw));
            acc0 = __builtin_amdgcn_mfma_f32_16x16x32_bf16(av0, bfr[ks], acc0, 0, 0, 0);
            acc1 = __builtin_amdgcn_mfma_f32_16x16x32_bf16(av1, bfr[ks + 1], acc1, 0, 0, 0);
        }
        // F: dump partials (C layout: col=lane&15, row=(lane>>4)*4+reg)
#pragma unroll
        for (int reg = 0; reg < 4; ++reg) {
            int crow = rt * 16 + ((lane >> 4) * 4) + reg;
            Pc[np][crow][lane & 15] = acc0[reg] + acc1[reg];
        }
        __syncthreads();

        // G: cell update; thread owns (erow, ejj); c stays in register
        {
            float gi = Pc[0][erow][ejj] + bI;
            float gf = Pc[1][erow][ejj] + bF;
            float gg = Pc[2][erow][ejj] + bG;
            float go = Pc[3][erow][ejj] + bO;
            float I = sigm(gi), F = sigm(gf), Gv = tanh_(gg), O = sigm(go);
            c_reg = F * c_reg + I * Gv;
            Hs[erow][ejj] = f2bf(O * tanh_(c_reg));
        }
        __syncthreads();

        // H: coherent write-through h stores (1KB tile), barrier drains all
        //    waves' vmcnt, then tid 0 publishes the flag (relaxed).
        if (tid < 128) {
            int row = tid >> 2, part = tid & 3;
            unsigned long long v = *(const unsigned long long*)(&Hs[row][part * 4]);
            __hip_atomic_store(
                (unsigned long long*)(hout + (size_t)(r0 + row) * H_ + cg * 16) + part,
                v, __ATOMIC_RELAXED, __HIP_MEMORY_SCOPE_AGENT);
        }
        __syncthreads();   // all h stores drained before flag
        if (tid == 0)
            __hip_atomic_store(myflag, (unsigned)(t + 1), __ATOMIC_RELAXED,
                               __HIP_MEMORY_SCOPE_AGENT);
    }
}

// ============ fallback per-step kernel (round-1, known passing) ============
__global__ __launch_bounds__(256) void lstm_step(const float* __restrict__ x,
                                                 const unsigned short* __restrict__ wpack,
                                                 const float* __restrict__ bias,
                                                 const unsigned short* __restrict__ hin,
                                                 unsigned short* __restrict__ hout,
                                                 float* __restrict__ cbuf,
                                                 int t) {
    __shared__ __align__(16) unsigned char As[64 * 1536];
    __shared__ __align__(16) unsigned char Ws[128 * 256];

    const int tid = threadIdx.x;
    const int w = tid >> 6, lane = tid & 63;
    const int r0 = blockIdx.x * 64;
    const int j0 = blockIdx.y * 32;

#pragma unroll
    for (int p = 0; p < 16; ++p) {
        int idx = p * 256 + tid;
        int row = idx >> 6, seg = idx & 63;
        uint4 v = *(const uint4*)(hin + (size_t)(r0 + row) * H_ + seg * 8);
        *(uint4*)(As + (((row * 1536) + seg * 16) ^ ((row & 7) << 4))) = v;
    }
#pragma unroll
    for (int p = 0; p < 8; ++p) {
        int idx = p * 256 + tid;
        int row = idx >> 5, seg = idx & 31;
        const float* sp = x + ((size_t)(r0 + row) * T_ + t) * D_ + seg * 8;
        float4 a = *(const float4*)sp;
        float4 b = *(const float4*)(sp + 4);
        union { unsigned short us[8]; uint4 v; } u;
        u.us[0] = f2bf(a.x); u.us[1] = f2bf(a.y); u.us[2] = f2bf(a.z); u.us[3] = f2bf(a.w);
        u.us[4] = f2bf(b.x); u.us[5] = f2bf(b.y); u.us[6] = f2bf(b.z); u.us[7] = f2bf(b.w);
        *(uint4*)(As + (((row * 1536) + 1024 + seg * 16) ^ ((row & 7) << 4))) = u.v;
    }
    __syncthreads();

    f32x4 acc[8];
#pragma unroll
    for (int i = 0; i < 8; ++i) acc[i] = (f32x4){0.f, 0.f, 0.f, 0.f};

    for (int kc = 0; kc < 6; ++kc) {
#pragma unroll
        for (int p = 0; p < 8; ++p) {
            int idx = p * 256 + tid;
            int n = idx >> 4, seg = idx & 15;
            int g = n >> 5, jj = n & 31;
            uint4 v = *(const uint4*)(wpack + (size_t)(g * H_ + j0 + jj) * KT_ + kc * 128 + seg * 8);
            *(uint4*)(Ws + (((n * 256) + seg * 16) ^ ((n & 7) << 4))) = v;
        }
        __syncthreads();
#pragma unroll
        for (int ks = 0; ks < 4; ++ks) {
            int row = w * 16 + (lane & 15);
            int kb = (kc * 128 + ks * 32 + ((lane >> 4) * 8)) * 2;
            bf16x8 av = *(const bf16x8*)(As + ((row * 1536 + kb) ^ ((row & 7) << 4)));
            int kwb = (ks * 32 + ((lane >> 4) * 8)) * 2;
#pragma unroll
            for (int nt = 0; nt < 8; ++nt) {
                int n = (nt >> 1) * 32 + (nt & 1) * 16 + (lane & 15);
                bf16x8 bv = *(const bf16x8*)(Ws + ((n * 256 + kwb) ^ ((n & 7) << 4)));
                acc[nt] = __builtin_amdgcn_mfma_f32_16x16x32_bf16(av, bv, acc[nt], 0, 0, 0);
            }
        }
        __syncthreads();
    }

#pragma unroll
    for (int jt = 0; jt < 2; ++jt) {
        int jc = j0 + jt * 16 + (lane & 15);
        float bi = bias[jc], bf = bias[H_ + jc], bg = bias[2 * H_ + jc], bo = bias[3 * H_ + jc];
        f32x4 ai = acc[0 * 2 + jt];
        f32x4 af = acc[1 * 2 + jt];
        f32x4 ag = acc[2 * 2 + jt];
        f32x4 ao = acc[3 * 2 + jt];
#pragma unroll
        for (int reg = 0; reg < 4; ++reg) {
            int rb = r0 + w * 16 + ((lane >> 4) * 4) + reg;
            float I = sigm(ai[reg] + bi);
            float F = sigm(af[reg] + bf);
            float Gv = tanh_(ag[reg] + bg);
            float O = sigm(ao[reg] + bo);
            size_t ci = (size_t)rb * H_ + jc;
            float cn = F * cbuf[ci] + I * Gv;
            cbuf[ci] = cn;
            hout[ci] = f2bf(O * tanh_(cn));
        }
    }
}

// ---- final: out = sigmoid(h @ W_out^T + b_out), [256,2] ----
__global__ __launch_bounds__(256) void classify(const unsigned short* __restrict__ hbuf,
                                                const float* __restrict__ Wout,
                                                const float* __restrict__ bout,
                                                float* __restrict__ out) {
    int r = threadIdx.x;
    float a0 = 0.f, a1 = 0.f;
    for (int kk = 0; kk < H_ / 8; ++kk) {
        union { unsigned short us[8]; uint4 v; } u;
        u.v = *(const uint4*)(hbuf + (size_t)r * H_ + kk * 8);
#pragma unroll
        for (int i = 0; i < 8; ++i) {
            float hf = bf2f(u.us[i]);
            int k = kk * 8 + i;
            a0 += hf * Wout[k];
            a1 += hf * Wout[H_ + k];
        }
    }
    out[r * 2 + 0] = sigm(a0 + bout[0]);
    out[r * 2 + 1] = sigm(a1 + bout[1]);
}

extern "C" void kernel_launch(void* const* d_in, const int* in_sizes, int n_in,
                              void* d_out, int out_size, void* d_ws, size_t ws_size,
                              hipStream_t stream) {
    const float* x    = (const float*)d_in[0];
    const float* Wih  = (const float*)d_in[1];
    const float* Whh  = (const float*)d_in[2];
    const float* bih  = (const float*)d_in[3];
    const float* bhh  = (const float*)d_in[4];
    const float* Wout = (const float*)d_in[5];
    const float* bout = (const float*)d_in[6];
    float* out = (float*)d_out;
    char* ws = (char*)d_ws;

    unsigned short* wpack = (unsigned short*)(ws + WPACK_OFF);
    float*          bias  = (float*)(ws + BIAS_OFF);
    unsigned short* h0    = (unsigned short*)(ws + H0_OFF);
    unsigned short* h1    = (unsigned short*)(ws + H1_OFF);
    float*          cbuf  = (float*)(ws + C_OFF);
    unsigned int*   flags = (unsigned int*)(ws + FLAG_OFF);

    build_wpack<<<768, 256, 0, stream>>>(Whh, Wih, wpack);
    init_misc<<<1024, 256, 0, stream>>>(bih, bhh, bias, (unsigned int*)(ws + H0_OFF), flags);

    // persistent cooperative kernel; fall back to per-step launches if rejected
    const float* xa = x; const unsigned short* wa = wpack; const float* ba = bias;
    unsigned short* h0a = h0; unsigned short* h1a = h1; unsigned int* fa = flags;
    void* args[] = { (void*)&xa, (void*)&wa, (void*)&ba, (void*)&h0a, (void*)&h1a, (void*)&fa };
    hipError_t e = hipLaunchCooperativeKernel((const void*)lstm_persist,
                                              dim3(256), dim3(512), args, 0, stream);
    if (e != hipSuccess) {
        for (int t = 0; t < T_; ++t) {
            const unsigned short* hin = (t & 1) ? h1 : h0;
            unsigned short*      hout = (t & 1) ? h0 : h1;
            lstm_step<<<dim3(4, 16), 256, 0, stream>>>(x, wpack, bias, hin, hout, cbuf, t);
        }
    }
    classify<<<1, 256, 0, stream>>>(h0, Wout, bout, out);
}

// Round 10
// 4550.900 us; speedup vs baseline: 2.5444x; 1.0526x over previous
//
#include <hip/hip_runtime.h>
#include <hip/hip_bf16.h>

#define B_  256
#define T_  1024
#define D_  256
#define H_  512
#define G_  2048   // 4*H
#define KT_ 768    // H + D

// ws layout (bytes)
#define WPACK_OFF 0                        // 2048*768*2 = 3145728
#define BIAS_OFF  3145728                  // 2048*4     = 8192
#define H0_OFF    (BIAS_OFF + 8192)        // 256*512*2  = 262144
#define H1_OFF    (H0_OFF + 262144)
#define C_OFF     (H1_OFF + 262144)        // 256*512*4  = 524288 (fallback path only)
#define FLAG_OFF  (C_OFF + 524288)         // 256 flags x 32 uints (128B apart) = 32768

typedef __attribute__((ext_vector_type(8))) short bf16x8;
typedef __attribute__((ext_vector_type(4))) float f32x4;

__device__ __forceinline__ unsigned short f2bf(float f) {
    unsigned int u = __float_as_uint(f);
    u = (u + 0x7fffu + ((u >> 16) & 1u)) >> 16;   // RNE
    return (unsigned short)u;
}
__device__ __forceinline__ float bf2f(unsigned short s) {
    return __uint_as_float(((unsigned int)s) << 16);
}
__device__ __forceinline__ float sigm(float v) { return 1.0f / (1.0f + __expf(-v)); }
__device__ __forceinline__ float tanh_(float v) { return 2.0f / (1.0f + __expf(-2.0f * v)) - 1.0f; }

// ---- prep: pack [W_hh | W_ih] rows into bf16 Wpack[2048][768] ----
__global__ __launch_bounds__(256) void build_wpack(const float* __restrict__ Whh,
                                                   const float* __restrict__ Wih,
                                                   unsigned short* __restrict__ wpack) {
    int idx = blockIdx.x * 256 + threadIdx.x;      // 0..196607, each = 8 elems
    int g = idx / 96, cc = idx % 96, k = cc * 8;
    const float* src = (k < H_) ? (Whh + (size_t)g * H_ + k)
                                : (Wih + (size_t)g * D_ + (k - H_));
    union { unsigned short us[8]; uint4 v; } u;
#pragma unroll
    for (int i = 0; i < 8; ++i) u.us[i] = f2bf(src[i]);
    *(uint4*)(wpack + (size_t)idx * 8) = u.v;
}

// ---- prep: zero h0/h1/c, build bias, zero flags ----
__global__ __launch_bounds__(256) void init_misc(const float* __restrict__ bih,
                                                 const float* __restrict__ bhh,
                                                 float* __restrict__ bias,
                                                 unsigned int* __restrict__ zreg,
                                                 unsigned int* __restrict__ flags) {
    int gid = blockIdx.x * 256 + threadIdx.x;      // grid 1024 -> 262144
    zreg[gid] = 0u;                                // h0+h1+c region (1 MB)
    if (gid < G_) bias[gid] = bih[gid] + bhh[gid];
    if (gid < 8192) flags[gid] = 0u;
}

// ============ persistent cooperative LSTM ============
// grid 256: rg = bid&7 (rowgroup, 32 batch rows), cg = bid>>3 (16 j-cols).
// 512 threads = 8 waves; wave w: np = w>>1 (gate), rt = w&1 (16-row tile).
// W fragments (24 x bf16x8 = 96 VGPR) in registers for the whole T loop.
// c lives in 1 reg/thread.
// h protocol (r9-proven, placement-independent):
//   producer: relaxed agent-scope stores -> __syncthreads (vmcnt drain)
//             -> relaxed flag store.
//   consumer: relaxed flag poll -> ONE acquire load (L1+L2 inv)
//             -> plain cached uint4 h loads (L2 serves co-located blocks).
// LDS padded (volatile -> not DCE'd) to 83KB so only 1 block/CU fits:
// 256 blocks spread over all 256 CUs.
__global__ __launch_bounds__(512, 2) void lstm_persist(
    const float* __restrict__ x,
    const unsigned short* __restrict__ wpack,
    const float* __restrict__ bias,
    unsigned short* __restrict__ h0,
    unsigned short* __restrict__ h1,
    unsigned int* __restrict__ flags)
{
    __shared__ __align__(16) unsigned char As[32 * 1536];   // [32 rows][768 k] bf16, XOR-swizzled
    __shared__ float Pc[4][32][18];                          // per-gate partial sums
    __shared__ unsigned char lds_pad[24 * 1024];             // force 1 block/CU (83KB total)

    const int tid  = threadIdx.x;
    const int lane = tid & 63, w = tid >> 6;
    const int np = w >> 1, rt = w & 1;
    const int rg = blockIdx.x & 7, cg = blockIdx.x >> 3;
    const int r0 = rg * 32;

    // volatile touch: compiler must keep the array -> LDS size is real
    ((volatile unsigned char*)lds_pad)[tid] = 0;

    // ---- load this wave's W fragments into registers (once) ----
    bf16x8 bfr[24];
    {
        const unsigned short* wrow = wpack
            + (size_t)(np * H_ + cg * 16 + (lane & 15)) * KT_ + ((lane >> 4) * 8);
#pragma unroll
        for (int ks = 0; ks < 24; ++ks) bfr[ks] = *(const bf16x8*)(wrow + ks * 32);
    }

    // ---- per-thread epilogue constants ----
    const int erow = tid >> 4;        // 0..31
    const int ejj  = tid & 15;        // 0..15
    const float bI = bias[0 * H_ + cg * 16 + ejj];
    const float bF = bias[1 * H_ + cg * 16 + ejj];
    const float bG = bias[2 * H_ + cg * 16 + ejj];
    const float bO = bias[3 * H_ + cg * 16 + ejj];
    float c_reg = 0.f;

    const int arow = rt * 16 + (lane & 15);
    const int koff = (lane >> 4) * 16;     // byte offset within 64B k-step
    const int asw  = (arow & 7) << 4;

    // ---- x prefetch (cached): 16 floats/thread ----
    const int xrow = tid >> 4;             // 0..31
    const int xd0  = (tid & 15) * 16;      // float index within row
    const float* xbase = x + (size_t)(r0 + xrow) * T_ * D_ + xd0;
    float4 pa = *(const float4*)(xbase + 0);
    float4 pb = *(const float4*)(xbase + 4);
    float4 pc2 = *(const float4*)(xbase + 8);
    float4 pd = *(const float4*)(xbase + 12);

    unsigned int* myflag   = flags + (size_t)(rg * 32 + cg) * 32;
    unsigned int* pollflag = flags + (size_t)(rg * 32 + (lane & 31)) * 32;

    for (int t = 0; t < T_; ++t) {
        const unsigned short* hin = (t & 1) ? h1 : h0;
        unsigned short*      hout = (t & 1) ? h0 : h1;

        // A: stage x(t) from prefetched regs -> As.x (k 512..767); prefetch x(t+1)
        {
            union { unsigned short us[8]; uint4 v; } u0, u1;
            u0.us[0] = f2bf(pa.x);  u0.us[1] = f2bf(pa.y);  u0.us[2] = f2bf(pa.z);  u0.us[3] = f2bf(pa.w);
            u0.us[4] = f2bf(pb.x);  u0.us[5] = f2bf(pb.y);  u0.us[6] = f2bf(pb.z);  u0.us[7] = f2bf(pb.w);
            u1.us[0] = f2bf(pc2.x); u1.us[1] = f2bf(pc2.y); u1.us[2] = f2bf(pc2.z); u1.us[3] = f2bf(pc2.w);
            u1.us[4] = f2bf(pd.x);  u1.us[5] = f2bf(pd.y);  u1.us[6] = f2bf(pd.z);  u1.us[7] = f2bf(pd.w);
            int kb = 1024 + xd0 * 2;
            int xsw = (xrow & 7) << 4;
            *(uint4*)(As + ((xrow * 1536 + kb) ^ xsw))      = u0.v;
            *(uint4*)(As + ((xrow * 1536 + kb + 16) ^ xsw)) = u1.v;
        }
        if (t + 1 < T_) {
            const float* sp = xbase + (size_t)(t + 1) * D_;
            pa = *(const float4*)(sp + 0);
            pb = *(const float4*)(sp + 4);
            pc2 = *(const float4*)(sp + 8);
            pd = *(const float4*)(sp + 12);
        }
        __syncthreads();

        // B1: first half of x-part MFMAs (ks 16..19) -- hides poll wait
        f32x4 acc0 = {0.f, 0.f, 0.f, 0.f}, acc1 = {0.f, 0.f, 0.f, 0.f};
#pragma unroll
        for (int ks = 16; ks < 20; ks += 2) {
            bf16x8 av0 = *(const bf16x8*)(As + ((arow * 1536 + ks * 64 + koff) ^ asw));
            bf16x8 av1 = *(const bf16x8*)(As + ((arow * 1536 + (ks + 1) * 64 + koff) ^ asw));
            acc0 = __builtin_amdgcn_mfma_f32_16x16x32_bf16(av0, bfr[ks], acc0, 0, 0, 0);
            acc1 = __builtin_amdgcn_mfma_f32_16x16x32_bf16(av1, bfr[ks + 1], acc1, 0, 0, 0);
        }

        // C: wave 0 polls the 32 rowgroup flags (relaxed), then ONE acquire
        //    load -> L1+L2 invalidate so phase D can use cached loads.
        if (w == 0 && t > 0) {
            while (true) {
                unsigned int f = __hip_atomic_load(pollflag, __ATOMIC_RELAXED,
                                                   __HIP_MEMORY_SCOPE_AGENT);
                if (__all((int)(f >= (unsigned)t))) break;
                __builtin_amdgcn_s_sleep(1);
            }
            (void)__hip_atomic_load(myflag, __ATOMIC_ACQUIRE, __HIP_MEMORY_SCOPE_AGENT);
        }
        __syncthreads();

        // D: issue cached 16B h loads (4/thread, 32KB) into regs; overlap the
        //    remaining x-part MFMAs (ks 20..23) with the load latency; then
        //    stage to As.h (compiler inserts the waitcnt before the ds_writes).
        {
            uint4 hv[4];
#pragma unroll
            for (int p = 0; p < 4; ++p) {
                int c = p * 512 + tid;            // 0..2047 chunks of 16B
                int row = c >> 6, off = c & 63;
                hv[p] = *(const uint4*)(hin + (size_t)(r0 + row) * H_ + off * 8);
            }
#pragma unroll
            for (int ks = 20; ks < 24; ks += 2) {
                bf16x8 av0 = *(const bf16x8*)(As + ((arow * 1536 + ks * 64 + koff) ^ asw));
                bf16x8 av1 = *(const bf16x8*)(As + ((arow * 1536 + (ks + 1) * 64 + koff) ^ asw));
                acc0 = __builtin_amdgcn_mfma_f32_16x16x32_bf16(av0, bfr[ks], acc0, 0, 0, 0);
                acc1 = __builtin_amdgcn_mfma_f32_16x16x32_bf16(av1, bfr[ks + 1], acc1, 0, 0, 0);
            }
#pragma unroll
            for (int p = 0; p < 4; ++p) {
                int c = p * 512 + tid;
                int row = c >> 6, off = c & 63;
                *(uint4*)(As + ((row * 1536 + off * 16) ^ ((row & 7) << 4))) = hv[p];
            }
        }
        __syncthreads();

        // E: h-part MFMAs (ks 0..15)
#pragma unroll
        for (int ks = 0; ks < 16; ks += 2) {
            bf16x8 av0 = *(const bf16x8*)(As + ((arow * 1536 + ks * 64 + koff) ^ asw));
            bf16x8 av1 = *(const bf16x8*)(As + ((arow * 1536 + (ks + 1) * 64 + koff) ^ asw));
            acc0 = __builtin_amdgcn_mfma_f32_16x16x32_bf16(av0, bfr[ks], acc0, 0, 0, 0);
            acc1 = __builtin_amdgcn_mfma_f32_16x16x32_bf16(av1, bfr[ks + 1], acc1, 0, 0, 0);
        }
        // F: dump partials (C layout: col=lane&15, row=(lane>>4)*4+reg)
#pragma unroll
        for (int reg = 0; reg < 4; ++reg) {
            int crow = rt * 16 + ((lane >> 4) * 4) + reg;
            Pc[np][crow][lane & 15] = acc0[reg] + acc1[reg];
        }
        __syncthreads();

        // G: cell update; thread owns (erow, ejj); c stays in register;
        //    direct 2B coherent h store (coalesces to 32B segments).
        {
            float gi = Pc[0][erow][ejj] + bI;
            float gf = Pc[1][erow][ejj] + bF;
            float gg = Pc[2][erow][ejj] + bG;
            float go = Pc[3][erow][ejj] + bO;
            float I = sigm(gi), F = sigm(gf), Gv = tanh_(gg), O = sigm(go);
            c_reg = F * c_reg + I * Gv;
            unsigned short hv16 = f2bf(O * tanh_(c_reg));
            __hip_atomic_store(hout + (size_t)(r0 + erow) * H_ + cg * 16 + ejj,
                               hv16, __ATOMIC_RELAXED, __HIP_MEMORY_SCOPE_AGENT);
        }
        __syncthreads();   // all threads' h stores drained before flag
        if (tid == 0)
            __hip_atomic_store(myflag, (unsigned)(t + 1), __ATOMIC_RELAXED,
                               __HIP_MEMORY_SCOPE_AGENT);
    }
}

// ============ fallback per-step kernel (round-1, known passing) ============
__global__ __launch_bounds__(256) void lstm_step(const float* __restrict__ x,
                                                 const unsigned short* __restrict__ wpack,
                                                 const float* __restrict__ bias,
                                                 const unsigned short* __restrict__ hin,
                                                 unsigned short* __restrict__ hout,
                                                 float* __restrict__ cbuf,
                                                 int t) {
    __shared__ __align__(16) unsigned char As[64 * 1536];
    __shared__ __align__(16) unsigned char Ws[128 * 256];

    const int tid = threadIdx.x;
    const int w = tid >> 6, lane = tid & 63;
    const int r0 = blockIdx.x * 64;
    const int j0 = blockIdx.y * 32;

#pragma unroll
    for (int p = 0; p < 16; ++p) {
        int idx = p * 256 + tid;
        int row = idx >> 6, seg = idx & 63;
        uint4 v = *(const uint4*)(hin + (size_t)(r0 + row) * H_ + seg * 8);
        *(uint4*)(As + (((row * 1536) + seg * 16) ^ ((row & 7) << 4))) = v;
    }
#pragma unroll
    for (int p = 0; p < 8; ++p) {
        int idx = p * 256 + tid;
        int row = idx >> 5, seg = idx & 31;
        const float* sp = x + ((size_t)(r0 + row) * T_ + t) * D_ + seg * 8;
        float4 a = *(const float4*)sp;
        float4 b = *(const float4*)(sp + 4);
        union { unsigned short us[8]; uint4 v; } u;
        u.us[0] = f2bf(a.x); u.us[1] = f2bf(a.y); u.us[2] = f2bf(a.z); u.us[3] = f2bf(a.w);
        u.us[4] = f2bf(b.x); u.us[5] = f2bf(b.y); u.us[6] = f2bf(b.z); u.us[7] = f2bf(b.w);
        *(uint4*)(As + (((row * 1536) + 1024 + seg * 16) ^ ((row & 7) << 4))) = u.v;
    }
    __syncthreads();

    f32x4 acc[8];
#pragma unroll
    for (int i = 0; i < 8; ++i) acc[i] = (f32x4){0.f, 0.f, 0.f, 0.f};

    for (int kc = 0; kc < 6; ++kc) {
#pragma unroll
        for (int p = 0; p < 8; ++p) {
            int idx = p * 256 + tid;
            int n = idx >> 4, seg = idx & 15;
            int g = n >> 5, jj = n & 31;
            uint4 v = *(const uint4*)(wpack + (size_t)(g * H_ + j0 + jj) * KT_ + kc * 128 + seg * 8);
            *(uint4*)(Ws + (((n * 256) + seg * 16) ^ ((n & 7) << 4))) = v;
        }
        __syncthreads();
#pragma unroll
        for (int ks = 0; ks < 4; ++ks) {
            int row = w * 16 + (lane & 15);
            int kb = (kc * 128 + ks * 32 + ((lane >> 4) * 8)) * 2;
            bf16x8 av = *(const bf16x8*)(As + ((row * 1536 + kb) ^ ((row & 7) << 4)));
            int kwb = (ks * 32 + ((lane >> 4) * 8)) * 2;
#pragma unroll
            for (int nt = 0; nt < 8; ++nt) {
                int n = (nt >> 1) * 32 + (nt & 1) * 16 + (lane & 15);
                bf16x8 bv = *(const bf16x8*)(Ws + ((n * 256 + kwb) ^ ((n & 7) << 4)));
                acc[nt] = __builtin_amdgcn_mfma_f32_16x16x32_bf16(av, bv, acc[nt], 0, 0, 0);
            }
        }
        __syncthreads();
    }

#pragma unroll
    for (int jt = 0; jt < 2; ++jt) {
        int jc = j0 + jt * 16 + (lane & 15);
        float bi = bias[jc], bf = bias[H_ + jc], bg = bias[2 * H_ + jc], bo = bias[3 * H_ + jc];
        f32x4 ai = acc[0 * 2 + jt];
        f32x4 af = acc[1 * 2 + jt];
        f32x4 ag = acc[2 * 2 + jt];
        f32x4 ao = acc[3 * 2 + jt];
#pragma unroll
        for (int reg = 0; reg < 4; ++reg) {
            int rb = r0 + w * 16 + ((lane >> 4) * 4) + reg;
            float I = sigm(ai[reg] + bi);
            float F = sigm(af[reg] + bf);
            float Gv = tanh_(ag[reg] + bg);
            float O = sigm(ao[reg] + bo);
            size_t ci = (size_t)rb * H_ + jc;
            float cn = F * cbuf[ci] + I * Gv;
            cbuf[ci] = cn;
            hout[ci] = f2bf(O * tanh_(cn));
        }
    }
}

// ---- final: out = sigmoid(h @ W_out^T + b_out), [256,2] ----
__global__ __launch_bounds__(256) void classify(const unsigned short* __restrict__ hbuf,
                                                const float* __restrict__ Wout,
                                                const float* __restrict__ bout,
                                                float* __restrict__ out) {
    int r = threadIdx.x;
    float a0 = 0.f, a1 = 0.f;
    for (int kk = 0; kk < H_ / 8; ++kk) {
        union { unsigned short us[8]; uint4 v; } u;
        u.v = *(const uint4*)(hbuf + (size_t)r * H_ + kk * 8);
#pragma unroll
        for (int i = 0; i < 8; ++i) {
            float hf = bf2f(u.us[i]);
            int k = kk * 8 + i;
            a0 += hf * Wout[k];
            a1 += hf * Wout[H_ + k];
        }
    }
    out[r * 2 + 0] = sigm(a0 + bout[0]);
    out[r * 2 + 1] = sigm(a1 + bout[1]);
}

extern "C" void kernel_launch(void* const* d_in, const int* in_sizes, int n_in,
                              void* d_out, int out_size, void* d_ws, size_t ws_size,
                              hipStream_t stream) {
    const float* x    = (const float*)d_in[0];
    const float* Wih  = (const float*)d_in[1];
    const float* Whh  = (const float*)d_in[2];
    const float* bih  = (const float*)d_in[3];
    const float* bhh  = (const float*)d_in[4];
    const float* Wout = (const float*)d_in[5];
    const float* bout = (const float*)d_in[6];
    float* out = (float*)d_out;
    char* ws = (char*)d_ws;

    unsigned short* wpack = (unsigned short*)(ws + WPACK_OFF);
    float*          bias  = (float*)(ws + BIAS_OFF);
    unsigned short* h0    = (unsigned short*)(ws + H0_OFF);
    unsigned short* h1    = (unsigned short*)(ws + H1_OFF);
    float*          cbuf  = (float*)(ws + C_OFF);
    unsigned int*   flags = (unsigned int*)(ws + FLAG_OFF);

    build_wpack<<<768, 256, 0, stream>>>(Whh, Wih, wpack);
    init_misc<<<1024, 256, 0, stream>>>(bih, bhh, bias, (unsigned int*)(ws + H0_OFF), flags);

    // persistent cooperative kernel; fall back to per-step launches if rejected
    const float* xa = x; const unsigned short* wa = wpack; const float* ba = bias;
    unsigned short* h0a = h0; unsigned short* h1a = h1; unsigned int* fa = flags;
    void* args[] = { (void*)&xa, (void*)&wa, (void*)&ba, (void*)&h0a, (void*)&h1a, (void*)&fa };
    hipError_t e = hipLaunchCooperativeKernel((const void*)lstm_persist,
                                              dim3(256), dim3(512), args, 0, stream);
    if (e != hipSuccess) {
        for (int t = 0; t < T_; ++t) {
            const unsigned short* hin = (t & 1) ? h1 : h0;
            unsigned short*      hout = (t & 1) ? h0 : h1;
            lstm_step<<<dim3(4, 16), 256, 0, stream>>>(x, wpack, bias, hin, hout, cbuf, t);
        }
    }
    classify<<<1, 256, 0, stream>>>(h0, Wout, bout, out);
}